// Round 9
// baseline (207.999 us; speedup 1.0000x reference)
//
#include <hip/hip_runtime.h>
#include <cstdint>
#include <cstddef>

// EdgeMessagePassingLayer: out = W @ (L @ rowsum(E)) + b
//   L[i,j] = 1 iff i!=j and exists k!=i,j with A[i,k]==A[j,k]==1.
// cnt[i,j] = popc(bits_i & bits_j) - d_i*M[j,i] - M[i,j]*d_j  (exact ints)
// EARLY EXIT: corrections <= 2, so partial popc >= 3 over ANY subset of k
// proves L=1 (if i!=j). Chunk 0 resolves ~all pairs; exact fallback otherwise.
// bits layout: chunk-major bitsT[32][4096] (uint4 = 128 bits per row-chunk).
//
// R9: consolidation at the measured budget: harness reset ~134 µs (derived
// from cross-round accounting), our floor ~40. Changes vs R6-best:
//  - no hipMemsetAsync node (prep zeroes agg)
//  - pack stores gathered to uint4 (8x16B vs 32x4B scattered per row)
//  - plain loads (no nontemporal: inputs are copy-restored, L2/L3-resident)

#define NN     4096
#define NCHUNK 32
#define TI     64            // i-rows per cnt block
#define STRIPJ 256           // j-rows per cnt block
#define NTHR   256

typedef unsigned int uint32;

// ---------------- fused prep ----------------
// blocks 0..2047    : pack A rows 2b, 2b+1
// blocks 2048..3071 : rowsum E rows 4q..4q+3
// block 0 also      : zero agg
__global__ __launch_bounds__(256) void prep_kernel(const float* __restrict__ A,
                                                   const float* __restrict__ E,
                                                   uint32* __restrict__ bitsT,
                                                   float* __restrict__ e,
                                                   float* __restrict__ agg) {
  const int b = blockIdx.x;
  const int t = threadIdx.x;
  if (b < NN / 2) {
    // ---- pack rows 2b,2b+1: col c = 256s + 4*lane + m; word q = cols [32q,+32) ----
    const int lane = t & 63;
    const int wv   = t >> 6;
#pragma unroll
    for (int r = 0; r < 2; ++r) {
      const int row = 2 * b + r;
      const float* arow = A + (size_t)row * NN;
#pragma unroll
      for (int s0 = 0; s0 < 4; ++s0) {
        const int s = wv + 4 * s0;
        float4 v = *reinterpret_cast<const float4*>(&arow[s * 256 + 4 * lane]);
        uint32 nib = (v.x == 1.0f ? 1u : 0u) | (v.y == 1.0f ? 2u : 0u)
                   | (v.z == 1.0f ? 4u : 0u) | (v.w == 1.0f ? 8u : 0u);
        uint32 w = nib << (4 * (lane & 7));
        w |= __shfl_xor(w, 1);
        w |= __shfl_xor(w, 2);
        w |= __shfl_xor(w, 4);            // lanes 8g..8g+7 all hold word widx = 8s+g
        // gather words of one 128-bit chunk to lanes 0 and 32:
        // chunk 2s+q (q=lane>>5) = words 8s+4q+0..3, held at lanes 32q+{0,8,16,24}
        const int qb = lane & 32;         // 0 or 32
        uint32 w0 = __shfl(w, qb + 0);
        uint32 w1 = __shfl(w, qb + 8);
        uint32 w2 = __shfl(w, qb + 16);
        uint32 w3 = __shfl(w, qb + 24);
        if ((lane & 31) == 0) {
          const int chunk = 2 * s + (lane >> 5);
          uint4 pkt; pkt.x = w0; pkt.y = w1; pkt.z = w2; pkt.w = w3;
          *reinterpret_cast<uint4*>(&bitsT[((size_t)chunk * NN + row) * 4]) = pkt;
        }
      }
    }
    if (b == 0) {
      float4 z = make_float4(0.f, 0.f, 0.f, 0.f);
      float4* a4 = reinterpret_cast<float4*>(agg);
      for (int k = t; k < NN / 4; k += NTHR) a4[k] = z;
    }
  } else {
    // ---- rowsum of E rows r0..r0+3 ----
    const int r0 = (b - NN / 2) * 4;
    const float* p0 = E + (size_t)r0 * NN;
    float s0 = 0.f, s1 = 0.f, s2 = 0.f, s3 = 0.f;
#pragma unroll
    for (int it = 0; it < 4; ++it) {
      const int k = (t + it * NTHR) * 4;
      float4 v0 = *reinterpret_cast<const float4*>(&p0[k]);
      float4 v1 = *reinterpret_cast<const float4*>(&p0[NN + k]);
      float4 v2 = *reinterpret_cast<const float4*>(&p0[2 * NN + k]);
      float4 v3 = *reinterpret_cast<const float4*>(&p0[3 * NN + k]);
      s0 += v0.x + v0.y + v0.z + v0.w;
      s1 += v1.x + v1.y + v1.z + v1.w;
      s2 += v2.x + v2.y + v2.z + v2.w;
      s3 += v3.x + v3.y + v3.z + v3.w;
    }
#pragma unroll
    for (int m = 1; m < 64; m <<= 1) {
      s0 += __shfl_xor(s0, m); s1 += __shfl_xor(s1, m);
      s2 += __shfl_xor(s2, m); s3 += __shfl_xor(s3, m);
    }
    __shared__ float red[4][4];
    if ((t & 63) == 0) {
      const int w = t >> 6;
      red[w][0] = s0; red[w][1] = s1; red[w][2] = s2; red[w][3] = s3;
    }
    __syncthreads();
    if (t < 4) e[r0 + t] = red[0][t] + red[1][t] + red[2][t] + red[3][t];
  }
}

// ---------------- main: agg[i] = sum_j L[i,j]*e[j], early-exit on chunk0 ----------------
__global__ __launch_bounds__(256) void cnt_agg_kernel(const uint32* __restrict__ bitsT,
                                                      const float* __restrict__ e,
                                                      float* __restrict__ agg) {
  __shared__ uint4 ic0[TI];        // chunk0 of i-rows   (1 KB)
  __shared__ uint4 jc0[STRIPJ];    // chunk0 of j-strip  (4 KB)
  __shared__ float es[STRIPJ];     // e[j] strip         (1 KB)

  const int t     = threadIdx.x;
  const int jbase = blockIdx.x * STRIPJ;
  const int i0    = blockIdx.y * TI;
  const uint4* bT4 = reinterpret_cast<const uint4*>(bitsT);

  if (t < TI) ic0[t] = bT4[i0 + t];
  jc0[t] = bT4[jbase + t];
  es[t]  = e[jbase + t];
  __syncthreads();

  const int ty = t >> 4;   // 16 i-groups of 4 rows
  const int tx = t & 15;   // j interleave

  uint4 iw[4];
#pragma unroll
  for (int r = 0; r < 4; ++r) iw[r] = ic0[ty * 4 + r];   // broadcast reads

  float acc[4] = {0.f, 0.f, 0.f, 0.f};

  for (int jj = 0; jj < STRIPJ / 16; ++jj) {
    const int jl = jj * 16 + tx;
    const int j  = jbase + jl;
    const uint4 jw = jc0[jl];
    const float ej = es[jl];
#pragma unroll
    for (int r = 0; r < 4; ++r) {
      const int i = i0 + ty * 4 + r;
      const int p = __popc(iw[r].x & jw.x) + __popc(iw[r].y & jw.y)
                  + __popc(iw[r].z & jw.z) + __popc(iw[r].w & jw.w);
      if (__builtin_expect(p > 2, 1)) {
        if (i != j) acc[r] += ej;          // cnt >= 3 > corrections(<=2)
      } else {
        int cnt = p;                        // exact fallback (L2-resident bits)
        for (int c = 1; c < NCHUNK; ++c) {
          const uint4 a  = bT4[(size_t)c * NN + i];
          const uint4 bb = bT4[(size_t)c * NN + j];
          cnt += __popc(a.x & bb.x) + __popc(a.y & bb.y)
               + __popc(a.z & bb.z) + __popc(a.w & bb.w);
        }
        const uint32 d_i = (bitsT[(((size_t)(i >> 7) * NN) + i) * 4 + ((i >> 5) & 3)] >> (i & 31)) & 1u;
        const uint32 Mji = (bitsT[(((size_t)(i >> 7) * NN) + j) * 4 + ((i >> 5) & 3)] >> (i & 31)) & 1u;
        const uint32 Mij = (bitsT[(((size_t)(j >> 7) * NN) + i) * 4 + ((j >> 5) & 3)] >> (j & 31)) & 1u;
        const uint32 d_j = (bitsT[(((size_t)(j >> 7) * NN) + j) * 4 + ((j >> 5) & 3)] >> (j & 31)) & 1u;
        const int cc = cnt - (int)(d_i * Mji) - (int)(Mij * d_j);
        if (cc > 0 && i != j) acc[r] += ej;
      }
    }
  }

#pragma unroll
  for (int m = 1; m < 16; m <<= 1)
#pragma unroll
    for (int r = 0; r < 4; ++r) acc[r] += __shfl_xor(acc[r], m);
  if (tx == 0) {
#pragma unroll
    for (int r = 0; r < 4; ++r) atomicAdd(&agg[i0 + ty * 4 + r], acc[r]);
  }
}

// ---------------- out[o] = dot(W[o,:], agg) + b[o], 2 outputs per block ----------------
__global__ __launch_bounds__(256) void matvec_kernel(const float* __restrict__ Wm,
                                                     const float* __restrict__ bvec,
                                                     const float* __restrict__ agg,
                                                     float* __restrict__ out) {
  const int o0 = blockIdx.x * 2;
  const float* w0 = Wm + (size_t)o0 * NN;
  const float* w1 = Wm + (size_t)(o0 + 1) * NN;
  const float4* ap = reinterpret_cast<const float4*>(agg);
  const int t = threadIdx.x;
  float s0 = 0.f, s1 = 0.f;
#pragma unroll
  for (int it = 0; it < 4; ++it) {
    const int k = t + it * NTHR;
    float4 a4 = ap[k];
    float4 x0 = *reinterpret_cast<const float4*>(&w0[k * 4]);
    float4 x1 = *reinterpret_cast<const float4*>(&w1[k * 4]);
    s0 += x0.x * a4.x + x0.y * a4.y + x0.z * a4.z + x0.w * a4.w;
    s1 += x1.x * a4.x + x1.y * a4.y + x1.z * a4.z + x1.w * a4.w;
  }
#pragma unroll
  for (int m = 1; m < 64; m <<= 1) { s0 += __shfl_xor(s0, m); s1 += __shfl_xor(s1, m); }
  __shared__ float red0[4], red1[4];
  if ((t & 63) == 0) { red0[t >> 6] = s0; red1[t >> 6] = s1; }
  __syncthreads();
  if (t == 0) {
    out[o0]     = red0[0] + red0[1] + red0[2] + red0[3] + bvec[o0];
    out[o0 + 1] = red1[0] + red1[1] + red1[2] + red1[3] + bvec[o0 + 1];
  }
}

extern "C" void kernel_launch(void* const* d_in, const int* in_sizes, int n_in,
                              void* d_out, int out_size, void* d_ws, size_t ws_size,
                              hipStream_t stream) {
  const float* A  = (const float*)d_in[0];   // [4096,4096] 0/1
  const float* E  = (const float*)d_in[1];   // [4096,4096]
  const float* Wm = (const float*)d_in[2];   // [4096,4096]
  const float* bv = (const float*)d_in[3];   // [4096]
  float* out = (float*)d_out;

  uint32* bitsT = (uint32*)d_ws;                                   // 2 MB (chunk-major)
  float*  e     = (float*)((char*)d_ws + (2u << 20));              // 16 KB
  float*  agg   = (float*)((char*)d_ws + (2u << 20) + 16384);      // 16 KB

  prep_kernel<<<NN / 2 + NN / 4, NTHR, 0, stream>>>(A, E, bitsT, e, agg);
  cnt_agg_kernel<<<dim3(NN / STRIPJ, NN / TI), NTHR, 0, stream>>>(bitsT, e, agg);
  matvec_kernel<<<NN / 2, NTHR, 0, stream>>>(Wm, bv, agg, out);
}

// Round 11
// 192.772 us; speedup vs baseline: 1.0790x; 1.0790x over previous
//
#include <hip/hip_runtime.h>
#include <cstdint>
#include <cstddef>

// EdgeMessagePassingLayer: out = W @ (L @ rowsum(E)) + b
//   L[i,j] = 1 iff i!=j and exists k!=i,j with A[i,k]==A[j,k]==1.
// cnt[i,j] = popc(bits_i & bits_j) - d_i*M[j,i] - M[i,j]*d_j  (exact ints)
// EARLY EXIT: corrections <= 2, so partial popc >= 3 over ANY subset of k
// proves L=1 (if i!=j). Chunk 0 (128 bits, mean popc 32 at p=0.25) resolves
// ~all pairs; exact full-popcount fallback otherwise.
// bits layout: chunk-major bitsT[32][4096] (uint4 = 128 bits per row-chunk).
//
// R11 = resubmit of R10 (GPU acquisition timed out; kernel never ran).
// R10 = exact revert to R6 (measured best, 192.7 µs). R9's deltas both
// regressed: no-nt loads + shfl-gather uint4 stores took prep 35->54 µs
// (VGPR 20->40, occupancy 63->44%). Keep: nt loads on streams, 1-row pack
// with 4B word stores, 2-row rowsum, agg zeroed by prep block 0.

#define NN     4096
#define NCHUNK 32
#define TI     64            // i-rows per cnt block
#define STRIPJ 256           // j-rows per cnt block
#define NTHR   256

typedef unsigned int uint32;
typedef float f32x4 __attribute__((ext_vector_type(4)));   // clang vector: ok for nontemporal builtin

// nontemporal float4 load via ext_vector_type (float4 struct is rejected by the builtin)
__device__ __forceinline__ float4 ntload4(const float* p) {
  f32x4 v = __builtin_nontemporal_load(reinterpret_cast<const f32x4*>(p));
  return make_float4(v.x, v.y, v.z, v.w);
}

// ---------------- fused prep ----------------
// blocks 0..4095    : pack row b of A (ballot-free nibble+shfl path)
// blocks 4096..6143 : rowsum of E rows 2q, 2q+1  (8 indep loads/thread)
// block 0 additionally : zero agg
__global__ __launch_bounds__(256) void prep_kernel(const float* __restrict__ A,
                                                   const float* __restrict__ E,
                                                   uint32* __restrict__ bitsT,
                                                   float* __restrict__ e,
                                                   float* __restrict__ agg) {
  const int b = blockIdx.x;
  const int t = threadIdx.x;
  if (b < NN) {
    // ---- pack: col c = 256s + 4*lane + m; word q covers cols [32q,32q+32) ----
    const int lane = t & 63;
    const int wv   = t >> 6;
    const float* arow = A + (size_t)b * NN;
#pragma unroll
    for (int s0 = 0; s0 < 4; ++s0) {
      const int s = wv + 4 * s0;          // 4 independent iterations per wave
      float4 v = ntload4(&arow[s * 256 + 4 * lane]);
      uint32 nib = (v.x == 1.0f ? 1u : 0u) | (v.y == 1.0f ? 2u : 0u)
                 | (v.z == 1.0f ? 4u : 0u) | (v.w == 1.0f ? 8u : 0u);
      uint32 w = nib << (4 * (lane & 7));
      w |= __shfl_xor(w, 1);
      w |= __shfl_xor(w, 2);
      w |= __shfl_xor(w, 4);              // every lane: full word of its 8-lane group
      if ((lane & 7) == 0) {
        const int widx = s * 8 + (lane >> 3);       // global word index (col>>5)
        bitsT[((size_t)(widx >> 2) * NN + b) * 4 + (widx & 3)] = w;
      }
    }
    if (b == 0) {
      float4 z = make_float4(0.f, 0.f, 0.f, 0.f);
      float4* a4 = reinterpret_cast<float4*>(agg);
      for (int k = t; k < NN / 4; k += NTHR) a4[k] = z;
    }
  } else {
    // ---- rowsum of E rows r0, r0+1 ----
    const int r0 = (b - NN) * 2;
    const float* p0 = E + (size_t)r0 * NN;
    const float* p1 = E + (size_t)(r0 + 1) * NN;
    float s0 = 0.f, s1 = 0.f;
#pragma unroll
    for (int it = 0; it < 4; ++it) {
      const int k = (t + it * NTHR) * 4;
      float4 v0 = ntload4(&p0[k]);
      float4 v1 = ntload4(&p1[k]);
      s0 += v0.x + v0.y + v0.z + v0.w;
      s1 += v1.x + v1.y + v1.z + v1.w;
    }
#pragma unroll
    for (int m = 1; m < 64; m <<= 1) { s0 += __shfl_xor(s0, m); s1 += __shfl_xor(s1, m); }
    __shared__ float red0[4], red1[4];
    if ((t & 63) == 0) { red0[t >> 6] = s0; red1[t >> 6] = s1; }
    __syncthreads();
    if (t == 0) {
      e[r0]     = red0[0] + red0[1] + red0[2] + red0[3];
      e[r0 + 1] = red1[0] + red1[1] + red1[2] + red1[3];
    }
  }
}

// ---------------- main: agg[i] = sum_j L[i,j]*e[j], early-exit on chunk0 ----------------
__global__ __launch_bounds__(256) void cnt_agg_kernel(const uint32* __restrict__ bitsT,
                                                      const float* __restrict__ e,
                                                      float* __restrict__ agg) {
  __shared__ uint4 ic0[TI];        // chunk0 of i-rows   (1 KB)
  __shared__ uint4 jc0[STRIPJ];    // chunk0 of j-strip  (4 KB)
  __shared__ float es[STRIPJ];     // e[j] strip         (1 KB)

  const int t     = threadIdx.x;
  const int jbase = blockIdx.x * STRIPJ;
  const int i0    = blockIdx.y * TI;
  const uint4* bT4 = reinterpret_cast<const uint4*>(bitsT);

  if (t < TI) ic0[t] = bT4[i0 + t];
  jc0[t] = bT4[jbase + t];
  es[t]  = e[jbase + t];
  __syncthreads();

  const int ty = t >> 4;   // 16 i-groups of 4 rows
  const int tx = t & 15;   // j interleave

  uint4 iw[4];
#pragma unroll
  for (int r = 0; r < 4; ++r) iw[r] = ic0[ty * 4 + r];   // broadcast reads

  float acc[4] = {0.f, 0.f, 0.f, 0.f};

  for (int jj = 0; jj < STRIPJ / 16; ++jj) {
    const int jl = jj * 16 + tx;
    const int j  = jbase + jl;
    const uint4 jw = jc0[jl];
    const float ej = es[jl];
#pragma unroll
    for (int r = 0; r < 4; ++r) {
      const int i = i0 + ty * 4 + r;
      const int p = __popc(iw[r].x & jw.x) + __popc(iw[r].y & jw.y)
                  + __popc(iw[r].z & jw.z) + __popc(iw[r].w & jw.w);
      if (__builtin_expect(p > 2, 1)) {
        if (i != j) acc[r] += ej;          // cnt >= 3 > corrections(<=2)
      } else {
        int cnt = p;                        // exact fallback (L2-resident bits)
        for (int c = 1; c < NCHUNK; ++c) {
          const uint4 a  = bT4[(size_t)c * NN + i];
          const uint4 bb = bT4[(size_t)c * NN + j];
          cnt += __popc(a.x & bb.x) + __popc(a.y & bb.y)
               + __popc(a.z & bb.z) + __popc(a.w & bb.w);
        }
        const uint32 d_i = (bitsT[(((size_t)(i >> 7) * NN) + i) * 4 + ((i >> 5) & 3)] >> (i & 31)) & 1u;
        const uint32 Mji = (bitsT[(((size_t)(i >> 7) * NN) + j) * 4 + ((i >> 5) & 3)] >> (i & 31)) & 1u;
        const uint32 Mij = (bitsT[(((size_t)(j >> 7) * NN) + i) * 4 + ((j >> 5) & 3)] >> (j & 31)) & 1u;
        const uint32 d_j = (bitsT[(((size_t)(j >> 7) * NN) + j) * 4 + ((j >> 5) & 3)] >> (j & 31)) & 1u;
        const int cc = cnt - (int)(d_i * Mji) - (int)(Mij * d_j);
        if (cc > 0 && i != j) acc[r] += ej;
      }
    }
  }

#pragma unroll
  for (int m = 1; m < 16; m <<= 1)
#pragma unroll
    for (int r = 0; r < 4; ++r) acc[r] += __shfl_xor(acc[r], m);
  if (tx == 0) {
#pragma unroll
    for (int r = 0; r < 4; ++r) atomicAdd(&agg[i0 + ty * 4 + r], acc[r]);
  }
}

// ---------------- out[o] = dot(W[o,:], agg) + b[o], 2 outputs per block ----------------
__global__ __launch_bounds__(256) void matvec_kernel(const float* __restrict__ Wm,
                                                     const float* __restrict__ bvec,
                                                     const float* __restrict__ agg,
                                                     float* __restrict__ out) {
  const int o0 = blockIdx.x * 2;
  const float* w0 = Wm + (size_t)o0 * NN;
  const float* w1 = Wm + (size_t)(o0 + 1) * NN;
  const float4* ap = reinterpret_cast<const float4*>(agg);
  const int t = threadIdx.x;
  float s0 = 0.f, s1 = 0.f;
#pragma unroll
  for (int it = 0; it < 4; ++it) {
    const int k = t + it * NTHR;
    float4 a4 = ap[k];                 // L2/L3-resident, not nt
    float4 x0 = ntload4(&w0[k * 4]);
    float4 x1 = ntload4(&w1[k * 4]);
    s0 += x0.x * a4.x + x0.y * a4.y + x0.z * a4.z + x0.w * a4.w;
    s1 += x1.x * a4.x + x1.y * a4.y + x1.z * a4.z + x1.w * a4.w;
  }
#pragma unroll
  for (int m = 1; m < 64; m <<= 1) { s0 += __shfl_xor(s0, m); s1 += __shfl_xor(s1, m); }
  __shared__ float red0[4], red1[4];
  if ((t & 63) == 0) { red0[t >> 6] = s0; red1[t >> 6] = s1; }
  __syncthreads();
  if (t == 0) {
    out[o0]     = red0[0] + red0[1] + red0[2] + red0[3] + bvec[o0];
    out[o0 + 1] = red1[0] + red1[1] + red1[2] + red1[3] + bvec[o0 + 1];
  }
}

extern "C" void kernel_launch(void* const* d_in, const int* in_sizes, int n_in,
                              void* d_out, int out_size, void* d_ws, size_t ws_size,
                              hipStream_t stream) {
  const float* A  = (const float*)d_in[0];   // [4096,4096] 0/1
  const float* E  = (const float*)d_in[1];   // [4096,4096]
  const float* Wm = (const float*)d_in[2];   // [4096,4096]
  const float* bv = (const float*)d_in[3];   // [4096]
  float* out = (float*)d_out;

  uint32* bitsT = (uint32*)d_ws;                                   // 2 MB (chunk-major)
  float*  e     = (float*)((char*)d_ws + (2u << 20));              // 16 KB
  float*  agg   = (float*)((char*)d_ws + (2u << 20) + 16384);      // 16 KB

  prep_kernel<<<NN + NN / 2, NTHR, 0, stream>>>(A, E, bitsT, e, agg);
  cnt_agg_kernel<<<dim3(NN / STRIPJ, NN / TI), NTHR, 0, stream>>>(bitsT, e, agg);
  matvec_kernel<<<NN / 2, NTHR, 0, stream>>>(Wm, bv, agg, out);
}